// Round 18
// baseline (429.469 us; speedup 1.0000x reference)
//
#include <hip/hip_runtime.h>
#include <stdint.h>

typedef unsigned long long u64;
typedef __attribute__((ext_vector_type(8))) short s16x8;     // 8 bf16 = 4 VGPRs
typedef __attribute__((ext_vector_type(4))) float f32x4v;
typedef __attribute__((ext_vector_type(4))) unsigned int u32x4;
typedef __attribute__((ext_vector_type(2))) unsigned int u32x2;

#define NB 8
#define NPTS 4096
#define NC 64
#define KOUT 16
#define TSEL 40          // preselect size; key err sigma ~0.04 << 8-rank gap ~1.5 (30+ sigma)
#define CHUNK 64         // candidate rows per staged chunk
#define NCHUNK (NPTS / CHUNK)
#define IDXBITS 0xFFFu
#define KEYMASK 0xFFFFF000u
#define RPW 4            // rows per wave (occupancy side of the RPW tradeoff)
#define RPB 16           // rows per block (4 waves)
#define ROWB 144         // bytes per Y LDS row: 64 bf16 (128B) + 16B pad (2-way banks = free)

// sq[p]: 8 accumulator chains over stride-8 (numpy pairwise-8 == XLA W8 reduce
// chains), separate mul/add roundings, combined ((r0+r1)+(r2+r3))+((r4+r5)+(r6+r7)).
__global__ __launch_bounds__(256) void sq_kernel(const float* __restrict__ pts,
                                                 float* __restrict__ sqw) {
    int p = blockIdx.x * 256 + threadIdx.x;
    const float* r = pts + (size_t)p * NC;
    float acc[8];
#pragma unroll
    for (int j = 0; j < 8; ++j) acc[j] = __fmul_rn(r[j], r[j]);
#pragma unroll
    for (int i = 8; i < 64; i += 8)
#pragma unroll
        for (int j = 0; j < 8; ++j)
            acc[j] = __fadd_rn(acc[j], __fmul_rn(r[i + j], r[i + j]));
    float s01 = __fadd_rn(acc[0], acc[1]);
    float s23 = __fadd_rn(acc[2], acc[3]);
    float s45 = __fadd_rn(acc[4], acc[5]);
    float s67 = __fadd_rn(acc[6], acc[7]);
    sqw[p] = __fadd_rn(__fadd_rn(s01, s23), __fadd_rn(s45, s67));
}

// pack two fp32 -> u32 of two bf16 (truncation; pure bit-move, b in high half)
static __device__ __forceinline__ uint32_t pkbf(float a, float b) {
#if __has_builtin(__builtin_amdgcn_perm)
    return __builtin_amdgcn_perm(__float_as_uint(b), __float_as_uint(a), 0x07060302);
#else
    return (__float_as_uint(b) & 0xFFFF0000u) | (__float_as_uint(a) >> 16);
#endif
}

// Maintain an ascending sorted 64-list, one u32 per lane:
// (fp32 key bits truncated to 20 | 12-bit idx). Key >= 0 so uint order == key
// order. Threshold = lane TSEL-1. PAIR-insert: two pending candidates per
// round -> serial ballot/bpermute chain halves. Both positions computed from
// independent ballots vs the SAME pre-shift list (plo=popc(<lo),
// phi=popc(<hi)+1); lanes select {keep, lo, shift1, hi, shift2}. The inserted
// SET is identical to serial insertion -> list invariant unchanged.
__device__ __forceinline__ void stream_insert(uint32_t& list, uint32_t cand, int lane) {
    uint32_t thr = (uint32_t)__builtin_amdgcn_readlane((int)list, TSEL - 1);
    u64 mask = __ballot(cand < thr);
    while (mask) {
        int s1 = __ffsll((long long)mask) - 1;
        mask &= (mask - 1);
        if (mask) {
            int s2 = __ffsll((long long)mask) - 1;
            mask &= (mask - 1);
            uint32_t v1 = (uint32_t)__builtin_amdgcn_readlane((int)cand, s1);
            uint32_t v2 = (uint32_t)__builtin_amdgcn_readlane((int)cand, s2);
            uint32_t lo = v1 < v2 ? v1 : v2;
            uint32_t hi = v1 < v2 ? v2 : v1;
            int plo = __popcll(__ballot(list < lo));
            int phi = __popcll(__ballot(list < hi)) + 1;   // hi lands after lo
            uint32_t up1 = __shfl_up(list, 1);             // independent pair:
            uint32_t up2 = __shfl_up(list, 2);             // one latency round
            uint32_t r = up2;                 // lane > phi
            r = (lane == phi) ? hi : r;
            r = (lane < phi) ? up1 : r;       // plo < lane < phi
            r = (lane == plo) ? lo : r;       // plo < phi always
            r = (lane < plo) ? list : r;
            list = r;
        } else {
            uint32_t v = (uint32_t)__builtin_amdgcn_readlane((int)cand, s1);
            int pos = __popcll(__ballot(list < v));
            uint32_t up = __shfl_up(list, 1);
            list = (lane < pos) ? list : ((lane == pos) ? v : up);
        }
    }
}

// Re-rank the TSEL preselected candidates by the emulated reference key:
// key = fl(fl(sq_n - fl(2*inner)) + sq_m), inner = ONE sequential FMA chain
// over k = 0..63 ascending (XLA:CPU dot_general / Eigen gebp order).
__device__ __forceinline__ void epilogue(uint32_t list, int n, int b, int lane,
                                         const float* __restrict__ pb,
                                         const float* __restrict__ sqb,
                                         float sqn,
                                         const float* __restrict__ xyz,
                                         float* __restrict__ out) {
    int m = (int)(list & IDXBITS);        // every lane holds a real index after chunk 0
    const float4* xr = (const float4*)(pb + (size_t)n * NC);
    const float4* yr = (const float4*)(pb + (size_t)m * NC);
    float acc = 0.f;
#pragma unroll
    for (int i = 0; i < 16; ++i) {
        float4 xv = xr[i];
        float4 yv = yr[i];
        acc = __fmaf_rn(xv.x, yv.x, acc);
        acc = __fmaf_rn(xv.y, yv.y, acc);
        acc = __fmaf_rn(xv.z, yv.z, acc);
        acc = __fmaf_rn(xv.w, yv.w, acc);
    }
    float key = __fadd_rn(__fsub_rn(sqn, __fmul_rn(2.0f, acc)), sqb[m]);

    int rank = 0;
    uint32_t kb = __float_as_uint(key);
#pragma unroll 1
    for (int j = 0; j < TSEL; ++j) {
        float kj = __uint_as_float(
            (uint32_t)__builtin_amdgcn_readlane((int)kb, j));
        int mj = __builtin_amdgcn_readlane(m, j);
        bool less = (kj < key) || (kj == key && mj < m);   // stable: lower idx first
        rank += less ? 1 : 0;
    }
    if (lane < TSEL && rank < 2 * KOUT && (rank & 1) == 0) {  // dilation D=2: even ranks
        int k = rank >> 1;
        const float* xn = xyz + ((size_t)b * NPTS + n) * 3;
        const float* xm = xyz + ((size_t)b * NPTS + m) * 3;
        float xnx = xn[0], xny = xn[1], xnz = xn[2];
        float ox = xm[0], oy = xm[1], oz = xm[2];
        float rx = xnx - ox, ry = xny - oy, rz = xnz - oz;
        float dis = sqrtf(rx * rx + ry * ry + rz * rz);
        float* o = out + (((size_t)b * NPTS + n) * KOUT + k) * 10;
        o[0] = dis; o[1] = rx; o[2] = ry; o[3] = rz;
        o[4] = xnx; o[5] = xny; o[6] = xnz;
        o[7] = ox;  o[8] = oy;  o[9] = oz;
    }
}

// MFMA preselect, tile-specialized, 16 rows/block, ONE barrier per chunk,
// slds double-buffered (publish(c+1) never races consume(c)). Per chunk:
// MFMA (reads ylds[cb]) -> publish slds[cb] -> stage ylds[cb^1] -> BARRIER ->
// consume slds[cb] + inserts. LDS 28.7 KB -> 5 blocks/CU -> 62% occupancy cap.
// C layout (m89): col=lane&15, row=(lane>>4)*4+reg.
// slds cand stride 80B: banks 20c mod 32 -> 2-way publish & consume (free).
__global__ __launch_bounds__(256, 3) void knn_kernel(
    const float* __restrict__ xyz,
    const float* __restrict__ pts,
    const float* __restrict__ sqw,
    float* __restrict__ out) {

    __shared__ __align__(16) unsigned short ylds[2][CHUNK * (ROWB / 2)];  // 18.4 KB bf16 dbuf
    __shared__ __align__(16) float slds[2][4][16][20];                    // 10.0 KB S-tile dbuf

    const int tid = threadIdx.x;
    const int lane = tid & 63;
    const int wave = tid >> 6;
    const int b = blockIdx.x >> 8;                  // 256 blocks per batch
    const int rowbase = (blockIdx.x & 255) << 4;    // 16 rows per block
    const int nw = __builtin_amdgcn_readfirstlane(rowbase + wave * RPW);
    const float* pb = pts + (size_t)b * NPTS * NC;
    const float* sqb = sqw + (size_t)b * NPTS;

    // A fragments (once per block): lane holds query row (lane&15), feats
    // (lane>>4)*8 + {0..7} (+32 for the K=32..63 fragment), packed bf16.
    s16x8 afrag0, afrag1;
    {
        const float* xrow = pb + (size_t)(rowbase + (lane & 15)) * NC + (lane >> 4) * 8;
        float4 xa0 = *(const float4*)(xrow);
        float4 xa1 = *(const float4*)(xrow + 4);
        float4 xb0 = *(const float4*)(xrow + 32);
        float4 xb1 = *(const float4*)(xrow + 36);
        u32x4 a0p = { pkbf(xa0.x, xa0.y), pkbf(xa0.z, xa0.w),
                      pkbf(xa1.x, xa1.y), pkbf(xa1.z, xa1.w) };
        u32x4 a1p = { pkbf(xb0.x, xb0.y), pkbf(xb0.z, xb0.w),
                      pkbf(xb1.x, xb1.y), pkbf(xb1.z, xb1.w) };
        afrag0 = __builtin_bit_cast(s16x8, a0p);
        afrag1 = __builtin_bit_cast(s16x8, a1p);
    }

    float sqn[RPW];
#pragma unroll
    for (int r = 0; r < RPW; ++r) sqn[r] = sqb[nw + r];   // uniform -> scalar loads

    uint32_t list[RPW];
#pragma unroll
    for (int r = 0; r < RPW; ++r) list[r] = 0xFFFFFFFFu;

    const float4* gsrc = (const float4*)pb;
    float4 pf[4];
#pragma unroll
    for (int j = 0; j < 4; ++j) pf[j] = gsrc[tid + 256 * j];   // prefetch chunk 0

    // stage chunk 0 into buffer 0 (fp32 -> bf16 pack)
#pragma unroll
    for (int j = 0; j < 4; ++j) {
        int s = tid + 256 * j;
        u32x2 w2 = { pkbf(pf[j].x, pf[j].y), pkbf(pf[j].z, pf[j].w) };
        *(u32x2*)((char*)ylds[0] + (s >> 4) * ROWB + (s & 15) * 8) = w2;
    }
    __syncthreads();

    for (int c = 0; c < NCHUNK; ++c) {
        const int cb = c & 1;
        if (c + 1 < NCHUNK) {
#pragma unroll
            for (int j = 0; j < 4; ++j)
                pf[j] = gsrc[(size_t)(c + 1) * (CHUNK * 16) + tid + 256 * j];
        }
        const int m = c * CHUNK + lane;
        float sqm = sqb[m];
        {
            // this wave's tile: cands 16*wave..16*wave+15, all 16 block rows
            const char* bp = (const char*)ylds[cb] + wave * (16 * ROWB)
                           + (lane & 15) * ROWB + (lane >> 4) * 16;
            s16x8 b0 = *(const s16x8*)(bp);        // K 0..31 fragment
            s16x8 b1 = *(const s16x8*)(bp + 64);   // K 32..63 fragment
            f32x4v cc = {0.f, 0.f, 0.f, 0.f};
            cc = __builtin_amdgcn_mfma_f32_16x16x32_bf16(afrag0, b0, cc, 0, 0, 0);
            cc = __builtin_amdgcn_mfma_f32_16x16x32_bf16(afrag1, b1, cc, 0, 0, 0);
            // publish: [cb][tile][cand][rows 4*(lane>>4)..+3]
            *(f32x4v*)&slds[cb][wave][lane & 15][(lane >> 4) * 4] = cc;
        }
        if (c + 1 < NCHUNK) {   // stage next chunk before the barrier
#pragma unroll
            for (int j = 0; j < 4; ++j) {
                int s = tid + 256 * j;
                u32x2 w2 = { pkbf(pf[j].x, pf[j].y), pkbf(pf[j].z, pf[j].w) };
                *(u32x2*)((char*)ylds[cb ^ 1] + (s >> 4) * ROWB + (s & 15) * 8) = w2;
            }
        }
        __syncthreads();   // tiles published AND next chunk staged
        {
            // lane's cand: tile lane>>4, col lane&15; this wave's rows 4w..4w+3
            f32x4v ip = *(const f32x4v*)&slds[cb][lane >> 4][lane & 15][wave * 4];
            float ipr[RPW] = { ip.x, ip.y, ip.z, ip.w };
#pragma unroll
            for (int r = 0; r < RPW; ++r) {
                float t = fmaxf(fmaf(-2.f, ipr[r], sqn[r] + sqm), 0.f);
                uint32_t cd = (__float_as_uint(t) & KEYMASK) | (unsigned)m;
                stream_insert(list[r], cd, lane);
            }
        }
    }

#pragma unroll 1
    for (int r = 0; r < RPW; ++r)
        epilogue(list[r], nw + r, b, lane, pb, sqb, sqn[r], xyz, out);
}

extern "C" void kernel_launch(void* const* d_in, const int* in_sizes, int n_in,
                              void* d_out, int out_size, void* d_ws, size_t ws_size,
                              hipStream_t stream) {
    const float* xyz = (const float*)d_in[0];   // [8,4096,3]
    const float* pts = (const float*)d_in[1];   // [8,4096,64]
    float* sqw = (float*)d_ws;                  // 32768 floats = 128 KB scratch
    float* out = (float*)d_out;                 // [8,4096,16,10]

    sq_kernel<<<(NB * NPTS) / 256, 256, 0, stream>>>(pts, sqw);
    knn_kernel<<<(NB * NPTS) / RPB, 256, 0, stream>>>(xyz, pts, sqw, out);
}

// Round 19
// 351.491 us; speedup vs baseline: 1.2218x; 1.2218x over previous
//
#include <hip/hip_runtime.h>
#include <stdint.h>

typedef unsigned long long u64;
typedef __attribute__((ext_vector_type(8))) short s16x8;     // 8 bf16 = 4 VGPRs
typedef __attribute__((ext_vector_type(4))) float f32x4v;
typedef __attribute__((ext_vector_type(4))) unsigned int u32x4;
typedef __attribute__((ext_vector_type(2))) unsigned int u32x2;

#define NB 8
#define NPTS 4096
#define NC 64
#define KOUT 16
#define TSEL 36          // preselect size; 4-rank margin ~0.76 vs key err sigma ~0.04 (19 sigma)
#define CHUNK 64         // candidate rows per staged chunk
#define NCHUNK (NPTS / CHUNK)
#define IDXBITS 0xFFFu
#define KEYMASK 0xFFFFF000u
#define RPW 4            // rows per wave (occupancy side of the RPW tradeoff)
#define RPB 16           // rows per block (4 waves)
#define ROWB 144         // bytes per Y LDS row: 64 bf16 (128B) + 16B pad (2-way banks = free)

// sq[p]: 8 accumulator chains over stride-8 (numpy pairwise-8 == XLA W8 reduce
// chains), separate mul/add roundings, combined ((r0+r1)+(r2+r3))+((r4+r5)+(r6+r7)).
__global__ __launch_bounds__(256) void sq_kernel(const float* __restrict__ pts,
                                                 float* __restrict__ sqw) {
    int p = blockIdx.x * 256 + threadIdx.x;
    const float* r = pts + (size_t)p * NC;
    float acc[8];
#pragma unroll
    for (int j = 0; j < 8; ++j) acc[j] = __fmul_rn(r[j], r[j]);
#pragma unroll
    for (int i = 8; i < 64; i += 8)
#pragma unroll
        for (int j = 0; j < 8; ++j)
            acc[j] = __fadd_rn(acc[j], __fmul_rn(r[i + j], r[i + j]));
    float s01 = __fadd_rn(acc[0], acc[1]);
    float s23 = __fadd_rn(acc[2], acc[3]);
    float s45 = __fadd_rn(acc[4], acc[5]);
    float s67 = __fadd_rn(acc[6], acc[7]);
    sqw[p] = __fadd_rn(__fadd_rn(s01, s23), __fadd_rn(s45, s67));
}

// pack two fp32 -> u32 of two bf16 (truncation; pure bit-move, b in high half)
static __device__ __forceinline__ uint32_t pkbf(float a, float b) {
#if __has_builtin(__builtin_amdgcn_perm)
    return __builtin_amdgcn_perm(__float_as_uint(b), __float_as_uint(a), 0x07060302);
#else
    return (__float_as_uint(b) & 0xFFFF0000u) | (__float_as_uint(a) >> 16);
#endif
}

// Maintain an ascending sorted 64-list, one u32 per lane:
// (fp32 key bits truncated to 20 | 12-bit idx). Key >= 0 so uint order == key
// order. Threshold = lane TSEL-1. Wave-parallel shift insert (r17-proven:
// the simple serial-hit form is issue-minimal; pair-insert measured -21%).
__device__ __forceinline__ void stream_insert(uint32_t& list, uint32_t cand, int lane) {
    uint32_t thr = (uint32_t)__builtin_amdgcn_readlane((int)list, TSEL - 1);
    u64 mask = __ballot(cand < thr);
    while (mask) {
        int src = __ffsll((long long)mask) - 1;
        uint32_t v = (uint32_t)__builtin_amdgcn_readlane((int)cand, src);  // uniform src
        int pos = __popcll(__ballot(list < v));
        uint32_t up = __shfl_up(list, 1);
        list = (lane < pos) ? list : ((lane == pos) ? v : up);
        mask &= (mask - 1);
    }
}

// Re-rank the TSEL preselected candidates by the emulated reference key:
// key = fl(fl(sq_n - fl(2*inner)) + sq_m), inner = ONE sequential FMA chain
// over k = 0..63 ascending (XLA:CPU dot_general / Eigen gebp order).
__device__ __forceinline__ void epilogue(uint32_t list, int n, int b, int lane,
                                         const float* __restrict__ pb,
                                         const float* __restrict__ sqb,
                                         float sqn,
                                         const float* __restrict__ xyz,
                                         float* __restrict__ out) {
    int m = (int)(list & IDXBITS);        // every lane holds a real index after chunk 0
    const float4* xr = (const float4*)(pb + (size_t)n * NC);
    const float4* yr = (const float4*)(pb + (size_t)m * NC);
    float acc = 0.f;
#pragma unroll
    for (int i = 0; i < 16; ++i) {
        float4 xv = xr[i];
        float4 yv = yr[i];
        acc = __fmaf_rn(xv.x, yv.x, acc);
        acc = __fmaf_rn(xv.y, yv.y, acc);
        acc = __fmaf_rn(xv.z, yv.z, acc);
        acc = __fmaf_rn(xv.w, yv.w, acc);
    }
    float key = __fadd_rn(__fsub_rn(sqn, __fmul_rn(2.0f, acc)), sqb[m]);

    int rank = 0;
    uint32_t kb = __float_as_uint(key);
#pragma unroll 1
    for (int j = 0; j < TSEL; ++j) {
        float kj = __uint_as_float(
            (uint32_t)__builtin_amdgcn_readlane((int)kb, j));
        int mj = __builtin_amdgcn_readlane(m, j);
        bool less = (kj < key) || (kj == key && mj < m);   // stable: lower idx first
        rank += less ? 1 : 0;
    }
    if (lane < TSEL && rank < 2 * KOUT && (rank & 1) == 0) {  // dilation D=2: even ranks
        int k = rank >> 1;
        const float* xn = xyz + ((size_t)b * NPTS + n) * 3;
        const float* xm = xyz + ((size_t)b * NPTS + m) * 3;
        float xnx = xn[0], xny = xn[1], xnz = xn[2];
        float ox = xm[0], oy = xm[1], oz = xm[2];
        float rx = xnx - ox, ry = xny - oy, rz = xnz - oz;
        float dis = sqrtf(rx * rx + ry * ry + rz * rz);
        float* o = out + (((size_t)b * NPTS + n) * KOUT + k) * 10;
        o[0] = dis; o[1] = rx; o[2] = ry; o[3] = rz;
        o[4] = xnx; o[5] = xny; o[6] = xnz;
        o[7] = ox;  o[8] = oy;  o[9] = oz;
    }
}

// MFMA preselect, tile-specialized, 16 rows/block, ONE barrier per chunk,
// slds double-buffered (publish(c+1) never races consume(c)). Per chunk:
// MFMA (reads ylds[cb]) -> publish slds[cb] -> stage ylds[cb^1] -> BARRIER ->
// consume slds[cb] + inserts. LDS 28.7 KB -> 5 blocks/CU -> 62% occupancy cap.
// C layout (m89): col=lane&15, row=(lane>>4)*4+reg.
// slds cand stride 80B: banks 20c mod 32 -> 2-way publish & consume (free).
__global__ __launch_bounds__(256, 3) void knn_kernel(
    const float* __restrict__ xyz,
    const float* __restrict__ pts,
    const float* __restrict__ sqw,
    float* __restrict__ out) {

    __shared__ __align__(16) unsigned short ylds[2][CHUNK * (ROWB / 2)];  // 18.4 KB bf16 dbuf
    __shared__ __align__(16) float slds[2][4][16][20];                    // 10.0 KB S-tile dbuf

    const int tid = threadIdx.x;
    const int lane = tid & 63;
    const int wave = tid >> 6;
    const int b = blockIdx.x >> 8;                  // 256 blocks per batch
    const int rowbase = (blockIdx.x & 255) << 4;    // 16 rows per block
    const int nw = __builtin_amdgcn_readfirstlane(rowbase + wave * RPW);
    const float* pb = pts + (size_t)b * NPTS * NC;
    const float* sqb = sqw + (size_t)b * NPTS;

    // A fragments (once per block): lane holds query row (lane&15), feats
    // (lane>>4)*8 + {0..7} (+32 for the K=32..63 fragment), packed bf16.
    s16x8 afrag0, afrag1;
    {
        const float* xrow = pb + (size_t)(rowbase + (lane & 15)) * NC + (lane >> 4) * 8;
        float4 xa0 = *(const float4*)(xrow);
        float4 xa1 = *(const float4*)(xrow + 4);
        float4 xb0 = *(const float4*)(xrow + 32);
        float4 xb1 = *(const float4*)(xrow + 36);
        u32x4 a0p = { pkbf(xa0.x, xa0.y), pkbf(xa0.z, xa0.w),
                      pkbf(xa1.x, xa1.y), pkbf(xa1.z, xa1.w) };
        u32x4 a1p = { pkbf(xb0.x, xb0.y), pkbf(xb0.z, xb0.w),
                      pkbf(xb1.x, xb1.y), pkbf(xb1.z, xb1.w) };
        afrag0 = __builtin_bit_cast(s16x8, a0p);
        afrag1 = __builtin_bit_cast(s16x8, a1p);
    }

    float sqn[RPW];
#pragma unroll
    for (int r = 0; r < RPW; ++r) sqn[r] = sqb[nw + r];   // uniform -> scalar loads

    uint32_t list[RPW];
#pragma unroll
    for (int r = 0; r < RPW; ++r) list[r] = 0xFFFFFFFFu;

    const float4* gsrc = (const float4*)pb;
    float4 pf[4];
#pragma unroll
    for (int j = 0; j < 4; ++j) pf[j] = gsrc[tid + 256 * j];   // prefetch chunk 0

    // stage chunk 0 into buffer 0 (fp32 -> bf16 pack)
#pragma unroll
    for (int j = 0; j < 4; ++j) {
        int s = tid + 256 * j;
        u32x2 w2 = { pkbf(pf[j].x, pf[j].y), pkbf(pf[j].z, pf[j].w) };
        *(u32x2*)((char*)ylds[0] + (s >> 4) * ROWB + (s & 15) * 8) = w2;
    }
    __syncthreads();

    for (int c = 0; c < NCHUNK; ++c) {
        const int cb = c & 1;
        if (c + 1 < NCHUNK) {
#pragma unroll
            for (int j = 0; j < 4; ++j)
                pf[j] = gsrc[(size_t)(c + 1) * (CHUNK * 16) + tid + 256 * j];
        }
        const int m = c * CHUNK + lane;
        float sqm = sqb[m];
        {
            // this wave's tile: cands 16*wave..16*wave+15, all 16 block rows
            const char* bp = (const char*)ylds[cb] + wave * (16 * ROWB)
                           + (lane & 15) * ROWB + (lane >> 4) * 16;
            s16x8 b0 = *(const s16x8*)(bp);        // K 0..31 fragment
            s16x8 b1 = *(const s16x8*)(bp + 64);   // K 32..63 fragment
            f32x4v cc = {0.f, 0.f, 0.f, 0.f};
            cc = __builtin_amdgcn_mfma_f32_16x16x32_bf16(afrag0, b0, cc, 0, 0, 0);
            cc = __builtin_amdgcn_mfma_f32_16x16x32_bf16(afrag1, b1, cc, 0, 0, 0);
            // publish: [cb][tile][cand][rows 4*(lane>>4)..+3]
            *(f32x4v*)&slds[cb][wave][lane & 15][(lane >> 4) * 4] = cc;
        }
        if (c + 1 < NCHUNK) {   // stage next chunk before the barrier
#pragma unroll
            for (int j = 0; j < 4; ++j) {
                int s = tid + 256 * j;
                u32x2 w2 = { pkbf(pf[j].x, pf[j].y), pkbf(pf[j].z, pf[j].w) };
                *(u32x2*)((char*)ylds[cb ^ 1] + (s >> 4) * ROWB + (s & 15) * 8) = w2;
            }
        }
        __syncthreads();   // tiles published AND next chunk staged
        {
            // lane's cand: tile lane>>4, col lane&15; this wave's rows 4w..4w+3
            f32x4v ip = *(const f32x4v*)&slds[cb][lane >> 4][lane & 15][wave * 4];
            float ipr[RPW] = { ip.x, ip.y, ip.z, ip.w };
#pragma unroll
            for (int r = 0; r < RPW; ++r) {
                float t = fmaxf(fmaf(-2.f, ipr[r], sqn[r] + sqm), 0.f);
                uint32_t cd = (__float_as_uint(t) & KEYMASK) | (unsigned)m;
                stream_insert(list[r], cd, lane);
            }
        }
    }

#pragma unroll 1
    for (int r = 0; r < RPW; ++r)
        epilogue(list[r], nw + r, b, lane, pb, sqb, sqn[r], xyz, out);
}

extern "C" void kernel_launch(void* const* d_in, const int* in_sizes, int n_in,
                              void* d_out, int out_size, void* d_ws, size_t ws_size,
                              hipStream_t stream) {
    const float* xyz = (const float*)d_in[0];   // [8,4096,3]
    const float* pts = (const float*)d_in[1];   // [8,4096,64]
    float* sqw = (float*)d_ws;                  // 32768 floats = 128 KB scratch
    float* out = (float*)d_out;                 // [8,4096,16,10]

    sq_kernel<<<(NB * NPTS) / 256, 256, 0, stream>>>(pts, sqw);
    knn_kernel<<<(NB * NPTS) / RPB, 256, 0, stream>>>(xyz, pts, sqw, out);
}

// Round 20
// 348.942 us; speedup vs baseline: 1.2308x; 1.0073x over previous
//
#include <hip/hip_runtime.h>
#include <stdint.h>

typedef unsigned long long u64;
typedef __attribute__((ext_vector_type(8))) short s16x8;     // 8 bf16 = 4 VGPRs
typedef __attribute__((ext_vector_type(4))) float f32x4v;
typedef __attribute__((ext_vector_type(4))) unsigned int u32x4;
typedef __attribute__((ext_vector_type(2))) unsigned int u32x2;

#define NB 8
#define NPTS 4096
#define NC 64
#define KOUT 16
#define TSEL 36          // preselect size; 4-rank margin ~0.76 vs key err sigma ~0.04 (19 sigma)
#define CHUNK 64         // candidate rows per staged chunk
#define NCHUNK (NPTS / CHUNK)
#define IDXBITS 0xFFFu
#define KEYMASK 0xFFFFF000u
#define RPW 4            // rows per wave
#define RPB 16           // rows per block (4 waves)
#define ROWB 144         // fallback path: padded row bytes

typedef const void __attribute__((address_space(1))) cvg_t;
typedef void __attribute__((address_space(3))) vl_t;
// async 16B global->LDS; linear source + linear dest (m97-proven pattern)
static __device__ __forceinline__ void async16(const void* g, void* l) {
    __builtin_amdgcn_global_load_lds((cvg_t*)g, (vl_t*)l, 16, 0, 0);
}

// sq[p]: 8 accumulator chains over stride-8 (numpy pairwise-8 == XLA W8 reduce
// chains), separate mul/add roundings, combined ((r0+r1)+(r2+r3))+((r4+r5)+(r6+r7)).
__global__ __launch_bounds__(256) void sq_kernel(const float* __restrict__ pts,
                                                 float* __restrict__ sqw) {
    int p = blockIdx.x * 256 + threadIdx.x;
    const float* r = pts + (size_t)p * NC;
    float acc[8];
#pragma unroll
    for (int j = 0; j < 8; ++j) acc[j] = __fmul_rn(r[j], r[j]);
#pragma unroll
    for (int i = 8; i < 64; i += 8)
#pragma unroll
        for (int j = 0; j < 8; ++j)
            acc[j] = __fadd_rn(acc[j], __fmul_rn(r[i + j], r[i + j]));
    float s01 = __fadd_rn(acc[0], acc[1]);
    float s23 = __fadd_rn(acc[2], acc[3]);
    float s45 = __fadd_rn(acc[4], acc[5]);
    float s67 = __fadd_rn(acc[6], acc[7]);
    sqw[p] = __fadd_rn(__fadd_rn(s01, s23), __fadd_rn(s45, s67));
}

// pack two fp32 -> u32 of two bf16 (truncation; pure bit-move, b in high half)
static __device__ __forceinline__ uint32_t pkbf(float a, float b) {
#if __has_builtin(__builtin_amdgcn_perm)
    return __builtin_amdgcn_perm(__float_as_uint(b), __float_as_uint(a), 0x07060302);
#else
    return (__float_as_uint(b) & 0xFFFF0000u) | (__float_as_uint(a) >> 16);
#endif
}

// Pre-pack pts -> bf16 with the bank-swizzle baked into the GLOBAL layout:
// row p's 16B feature-block fb is stored at block fb ^ (p&7). Identical pkbf
// truncation to the old in-loop staging -> keys bit-identical.
__global__ __launch_bounds__(256) void cvt_kernel(const float* __restrict__ pts,
                                                  uint32_t* __restrict__ bfw) {
    int t = blockIdx.x * 256 + threadIdx.x;
    int p = t >> 5;          // point row
    int q = t & 31;          // output u32 slot within row
    int j = ((((q >> 2) ^ (p & 7)) << 2) | (q & 3));   // source u32 (feat pair)
    const float* r = pts + (size_t)p * NC + 2 * j;
    bfw[(size_t)p * 32 + q] = pkbf(r[0], r[1]);
}

// Maintain an ascending sorted 64-list, one u32 per lane:
// (fp32 key bits truncated to 20 | 12-bit idx). Key >= 0 so uint order == key
// order. Threshold = lane TSEL-1. Wave-parallel shift insert (r17-proven:
// the simple serial-hit form is issue-minimal; pair-insert measured -21%).
__device__ __forceinline__ void stream_insert(uint32_t& list, uint32_t cand, int lane) {
    uint32_t thr = (uint32_t)__builtin_amdgcn_readlane((int)list, TSEL - 1);
    u64 mask = __ballot(cand < thr);
    while (mask) {
        int src = __ffsll((long long)mask) - 1;
        uint32_t v = (uint32_t)__builtin_amdgcn_readlane((int)cand, src);  // uniform src
        int pos = __popcll(__ballot(list < v));
        uint32_t up = __shfl_up(list, 1);
        list = (lane < pos) ? list : ((lane == pos) ? v : up);
        mask &= (mask - 1);
    }
}

// Re-rank the TSEL preselected candidates by the emulated reference key:
// key = fl(fl(sq_n - fl(2*inner)) + sq_m), inner = ONE sequential FMA chain
// over k = 0..63 ascending (XLA:CPU dot_general / Eigen gebp order).
__device__ __forceinline__ void epilogue(uint32_t list, int n, int b, int lane,
                                         const float* __restrict__ pb,
                                         const float* __restrict__ sqb,
                                         float sqn,
                                         const float* __restrict__ xyz,
                                         float* __restrict__ out) {
    int m = (int)(list & IDXBITS);        // every lane holds a real index after chunk 0
    const float4* xr = (const float4*)(pb + (size_t)n * NC);
    const float4* yr = (const float4*)(pb + (size_t)m * NC);
    float acc = 0.f;
#pragma unroll
    for (int i = 0; i < 16; ++i) {
        float4 xv = xr[i];
        float4 yv = yr[i];
        acc = __fmaf_rn(xv.x, yv.x, acc);
        acc = __fmaf_rn(xv.y, yv.y, acc);
        acc = __fmaf_rn(xv.z, yv.z, acc);
        acc = __fmaf_rn(xv.w, yv.w, acc);
    }
    float key = __fadd_rn(__fsub_rn(sqn, __fmul_rn(2.0f, acc)), sqb[m]);

    int rank = 0;
    uint32_t kb = __float_as_uint(key);
#pragma unroll 1
    for (int j = 0; j < TSEL; ++j) {
        float kj = __uint_as_float(
            (uint32_t)__builtin_amdgcn_readlane((int)kb, j));
        int mj = __builtin_amdgcn_readlane(m, j);
        bool less = (kj < key) || (kj == key && mj < m);   // stable: lower idx first
        rank += less ? 1 : 0;
    }
    if (lane < TSEL && rank < 2 * KOUT && (rank & 1) == 0) {  // dilation D=2: even ranks
        int k = rank >> 1;
        const float* xn = xyz + ((size_t)b * NPTS + n) * 3;
        const float* xm = xyz + ((size_t)b * NPTS + m) * 3;
        float xnx = xn[0], xny = xn[1], xnz = xn[2];
        float ox = xm[0], oy = xm[1], oz = xm[2];
        float rx = xnx - ox, ry = xny - oy, rz = xnz - oz;
        float dis = sqrtf(rx * rx + ry * ry + rz * rz);
        float* o = out + (((size_t)b * NPTS + n) * KOUT + k) * 10;
        o[0] = dis; o[1] = rx; o[2] = ry; o[3] = rz;
        o[4] = xnx; o[5] = xny; o[6] = xnz;
        o[7] = ox;  o[8] = oy;  o[9] = oz;
    }
}

// MFMA preselect, tile-specialized, 16 rows/block, ONE barrier per chunk,
// slds double-buffered. PRE=true: ylds staged from the pre-packed swizzled
// bf16 copy via global_load_lds (no in-loop pkbf/ds_write; 128B rows, LDS
// 26 KB -> 6 blocks/CU). PRE=false: r19 fallback (pf + pkbf staging) when
// the workspace can't hold the bf16 copy.
// C layout (m89): col=lane&15, row=(lane>>4)*4+reg.
template<bool PRE>
__global__ __launch_bounds__(256, 3) void knn_kernel(
    const float* __restrict__ xyz,
    const float* __restrict__ pts,
    const float* __restrict__ sqw,
    const unsigned short* __restrict__ bfw,
    float* __restrict__ out) {

    __shared__ __align__(16) unsigned short ylds[2][CHUNK * (PRE ? 64 : 72)];
    __shared__ __align__(16) float slds[2][4][16][20];    // 10.0 KB S-tile dbuf

    const int tid = threadIdx.x;
    const int lane = tid & 63;
    const int wave = tid >> 6;
    const int b = blockIdx.x >> 8;                  // 256 blocks per batch
    const int rowbase = (blockIdx.x & 255) << 4;    // 16 rows per block
    const int nw = __builtin_amdgcn_readfirstlane(rowbase + wave * RPW);
    const float* pb = pts + (size_t)b * NPTS * NC;
    const float* sqb = sqw + (size_t)b * NPTS;

    // A fragments (once per block): lane holds query row (lane&15), feats
    // (lane>>4)*8 + {0..7} (+32 for the K=32..63 fragment), packed bf16.
    s16x8 afrag0, afrag1;
    {
        const float* xrow = pb + (size_t)(rowbase + (lane & 15)) * NC + (lane >> 4) * 8;
        float4 xa0 = *(const float4*)(xrow);
        float4 xa1 = *(const float4*)(xrow + 4);
        float4 xb0 = *(const float4*)(xrow + 32);
        float4 xb1 = *(const float4*)(xrow + 36);
        u32x4 a0p = { pkbf(xa0.x, xa0.y), pkbf(xa0.z, xa0.w),
                      pkbf(xa1.x, xa1.y), pkbf(xa1.z, xa1.w) };
        u32x4 a1p = { pkbf(xb0.x, xb0.y), pkbf(xb0.z, xb0.w),
                      pkbf(xb1.x, xb1.y), pkbf(xb1.z, xb1.w) };
        afrag0 = __builtin_bit_cast(s16x8, a0p);
        afrag1 = __builtin_bit_cast(s16x8, a1p);
    }

    float sqn[RPW];
#pragma unroll
    for (int r = 0; r < RPW; ++r) sqn[r] = sqb[nw + r];   // uniform -> scalar loads

    uint32_t list[RPW];
#pragma unroll
    for (int r = 0; r < RPW; ++r) list[r] = 0xFFFFFFFFu;

    const float4* gsrc = (const float4*)pb;
    const char* gbf = (const char*)(bfw + (size_t)b * NPTS * NC);
    float4 pf[4];   // fallback path only (DCE'd when PRE)

    if constexpr (PRE) {
        async16(gbf + tid * 16, (char*)ylds[0] + tid * 16);
        async16(gbf + 4096 + tid * 16, (char*)ylds[0] + 4096 + tid * 16);
    } else {
#pragma unroll
        for (int j = 0; j < 4; ++j) pf[j] = gsrc[tid + 256 * j];
#pragma unroll
        for (int j = 0; j < 4; ++j) {
            int s = tid + 256 * j;
            u32x2 w2 = { pkbf(pf[j].x, pf[j].y), pkbf(pf[j].z, pf[j].w) };
            *(u32x2*)((char*)ylds[0] + (s >> 4) * ROWB + (s & 15) * 8) = w2;
        }
    }
    __syncthreads();

    for (int c = 0; c < NCHUNK; ++c) {
        const int cb = c & 1;
        if (c + 1 < NCHUNK) {
            if constexpr (PRE) {
                // stage next chunk: 8 KB, linear src (swizzle baked in) -> linear dest
                const char* gs = gbf + (size_t)(c + 1) * (CHUNK * NC * 2);
                char* lb = (char*)ylds[cb ^ 1];
                async16(gs + tid * 16, lb + tid * 16);
                async16(gs + 4096 + tid * 16, lb + 4096 + tid * 16);
            } else {
#pragma unroll
                for (int j = 0; j < 4; ++j)
                    pf[j] = gsrc[(size_t)(c + 1) * (CHUNK * 16) + tid + 256 * j];
            }
        }
        const int m = c * CHUNK + lane;
        float sqm = sqb[m];
        {
            // this wave's tile: cands 16*wave..16*wave+15, all 16 block rows
            s16x8 b0, b1;
            if constexpr (PRE) {
                const char* yb = (const char*)ylds[cb] + wave * (16 * 128)
                               + (lane & 15) * 128;
                const int bx = lane & 7;    // swizzle: block fb stored at fb^(row&7)
                b0 = *(const s16x8*)(yb + ((((lane >> 4)    ) ^ bx) << 4));  // K 0..31
                b1 = *(const s16x8*)(yb + ((((lane >> 4) + 4) ^ bx) << 4));  // K 32..63
            } else {
                const char* bp = (const char*)ylds[cb] + wave * (16 * ROWB)
                               + (lane & 15) * ROWB + (lane >> 4) * 16;
                b0 = *(const s16x8*)(bp);
                b1 = *(const s16x8*)(bp + 64);
            }
            f32x4v cc = {0.f, 0.f, 0.f, 0.f};
            cc = __builtin_amdgcn_mfma_f32_16x16x32_bf16(afrag0, b0, cc, 0, 0, 0);
            cc = __builtin_amdgcn_mfma_f32_16x16x32_bf16(afrag1, b1, cc, 0, 0, 0);
            // publish: [cb][tile][cand][rows 4*(lane>>4)..+3]
            *(f32x4v*)&slds[cb][wave][lane & 15][(lane >> 4) * 4] = cc;
        }
        if constexpr (!PRE) {
            if (c + 1 < NCHUNK) {
#pragma unroll
                for (int j = 0; j < 4; ++j) {
                    int s = tid + 256 * j;
                    u32x2 w2 = { pkbf(pf[j].x, pf[j].y), pkbf(pf[j].z, pf[j].w) };
                    *(u32x2*)((char*)ylds[cb ^ 1] + (s >> 4) * ROWB + (s & 15) * 8) = w2;
                }
            }
        }
        __syncthreads();   // tiles published AND next chunk staged (vmcnt drained)
        {
            // lane's cand: tile lane>>4, col lane&15; this wave's rows 4w..4w+3
            f32x4v ip = *(const f32x4v*)&slds[cb][lane >> 4][lane & 15][wave * 4];
            float ipr[RPW] = { ip.x, ip.y, ip.z, ip.w };
#pragma unroll
            for (int r = 0; r < RPW; ++r) {
                float t = fmaxf(fmaf(-2.f, ipr[r], sqn[r] + sqm), 0.f);
                uint32_t cd = (__float_as_uint(t) & KEYMASK) | (unsigned)m;
                stream_insert(list[r], cd, lane);
            }
        }
    }

#pragma unroll 1
    for (int r = 0; r < RPW; ++r)
        epilogue(list[r], nw + r, b, lane, pb, sqb, sqn[r], xyz, out);
}

extern "C" void kernel_launch(void* const* d_in, const int* in_sizes, int n_in,
                              void* d_out, int out_size, void* d_ws, size_t ws_size,
                              hipStream_t stream) {
    const float* xyz = (const float*)d_in[0];   // [8,4096,3]
    const float* pts = (const float*)d_in[1];   // [8,4096,64]
    float* sqw = (float*)d_ws;                  // 128 KB
    float* out = (float*)d_out;                 // [8,4096,16,10]

    sq_kernel<<<(NB * NPTS) / 256, 256, 0, stream>>>(pts, sqw);

    const size_t need = 32768 * sizeof(float) + (size_t)NB * NPTS * NC * 2;
    if (ws_size >= need) {
        unsigned short* bfw = (unsigned short*)((char*)d_ws + 32768 * sizeof(float));
        cvt_kernel<<<(NB * NPTS * 32) / 256, 256, 0, stream>>>(pts, (uint32_t*)bfw);
        knn_kernel<true><<<(NB * NPTS) / RPB, 256, 0, stream>>>(xyz, pts, sqw, bfw, out);
    } else {
        knn_kernel<false><<<(NB * NPTS) / RPB, 256, 0, stream>>>(xyz, pts, sqw, nullptr, out);
    }
}